// Round 2
// baseline (228.464 us; speedup 1.0000x reference)
//
#include <hip/hip_runtime.h>

// ---------------------------------------------------------------------------
// AttentionLayer: q=relu(x1@Wq+bq)/8, k=relu(x2@Wk+bk), v=relu(x2@Wv+bv)
//   out = softmax(mask(q@k^T)) @ v          B=4, S=4096, D=512, dk=64
// Plan: kernel 1 projects q,k (row-major [B*S][64] f16) and vT ([B][64][S] f16)
//       kernel 2 = flash attention, fp16 MFMA 16x16x32, online softmax.
// Fragment layout assumptions (see round notes):
//   A/B frag: row|col = lane&15, k = 8*(lane>>4)+e  (contiguous 8 f16 = b128)
//   C/D frag: col = lane&15,     row = 4*(lane>>4)+r   (m89-verified)
// ---------------------------------------------------------------------------

typedef __attribute__((ext_vector_type(8))) _Float16 f16x8;
typedef __attribute__((ext_vector_type(4))) float f32x4;
typedef __attribute__((ext_vector_type(8))) unsigned short us8;
typedef __attribute__((ext_vector_type(4))) unsigned short us4;

__device__ __forceinline__ unsigned short f2h(float f) {
  _Float16 h = (_Float16)f;  // RNE
  return __builtin_bit_cast(unsigned short, h);
}

#define S_LEN 4096
#define NROW 16384  // B*S

// ---------------------------------------------------------------------------
// Projection: grid (128 row-tiles, 3 projections), 256 threads.
// Tile: 128 rows x 64 cols, K loop over 512 in BK=64 chunks, MFMA f16.
// ---------------------------------------------------------------------------
__global__ __launch_bounds__(256) void proj_kernel(
    const float* __restrict__ x1, const float* __restrict__ x2,
    const float* __restrict__ Wq, const float* __restrict__ bq,
    const float* __restrict__ Wk, const float* __restrict__ bk,
    const float* __restrict__ Wv, const float* __restrict__ bv,
    unsigned short* __restrict__ qo, unsigned short* __restrict__ ko,
    unsigned short* __restrict__ vto) {
  const int p = blockIdx.y;
  const float* __restrict__ X = (p == 0) ? x1 : x2;
  const float* __restrict__ W = (p == 0) ? Wq : (p == 1) ? Wk : Wv;
  const float* __restrict__ bias = (p == 0) ? bq : (p == 1) ? bk : bv;
  const int row0 = blockIdx.x * 128;

  __shared__ __align__(16) unsigned short As[128][72];  // x tile, f16 bits, +8 pad
  __shared__ __align__(16) unsigned short Wt[64][72];   // W^T tile [n][k]

  const int t = threadIdx.x;
  const int l = t & 63, w = t >> 6, lm = l & 15, lg = l >> 4;

  f32x4 acc[2][4];
#pragma unroll
  for (int i = 0; i < 2; i++)
#pragma unroll
    for (int j = 0; j < 4; j++)
#pragma unroll
      for (int e = 0; e < 4; e++) acc[i][j][e] = 0.0f;

  for (int k0 = 0; k0 < 512; k0 += 64) {
    if (k0) __syncthreads();
    // stage x tile: 128x64 fp32 -> f16 LDS (8 float4 per thread)
#pragma unroll
    for (int i = 0; i < 8; i++) {
      int f = t + 256 * i;              // 0..2047 float4 slots
      int r = f >> 4, c4 = (f & 15) << 2;
      float4 v4 = *(const float4*)&X[(size_t)(row0 + r) * 512 + k0 + c4];
      us4 b;
      b[0] = f2h(v4.x); b[1] = f2h(v4.y); b[2] = f2h(v4.z); b[3] = f2h(v4.w);
      *(us4*)&As[r][c4] = b;
    }
    // stage W^T tile: read W[k][n] rows coalesced, scatter-write transposed
#pragma unroll
    for (int i = 0; i < 4; i++) {
      int f = t + 256 * i;              // 0..1023
      int kk = f >> 4, c4 = (f & 15) << 2;
      float4 v4 = *(const float4*)&W[(size_t)(k0 + kk) * 64 + c4];
      Wt[c4 + 0][kk] = f2h(v4.x);
      Wt[c4 + 1][kk] = f2h(v4.y);
      Wt[c4 + 2][kk] = f2h(v4.z);
      Wt[c4 + 3][kk] = f2h(v4.w);
    }
    __syncthreads();

    f16x8 af[2][2], bfr[4][2];
#pragma unroll
    for (int im = 0; im < 2; im++)
#pragma unroll
      for (int kk = 0; kk < 2; kk++)
        af[im][kk] = *(const f16x8*)&As[32 * w + 16 * im + lm][kk * 32 + 8 * lg];
#pragma unroll
    for (int nt = 0; nt < 4; nt++)
#pragma unroll
      for (int kk = 0; kk < 2; kk++)
        bfr[nt][kk] = *(const f16x8*)&Wt[16 * nt + lm][kk * 32 + 8 * lg];
#pragma unroll
    for (int im = 0; im < 2; im++)
#pragma unroll
      for (int nt = 0; nt < 4; nt++) {
        acc[im][nt] = __builtin_amdgcn_mfma_f32_16x16x32_f16(af[im][0], bfr[nt][0], acc[im][nt], 0, 0, 0);
        acc[im][nt] = __builtin_amdgcn_mfma_f32_16x16x32_f16(af[im][1], bfr[nt][1], acc[im][nt], 0, 0, 0);
      }
  }

  const float scale = (p == 0) ? 0.125f : 1.0f;  // fold 1/sqrt(64) into q
#pragma unroll
  for (int im = 0; im < 2; im++)
#pragma unroll
    for (int nt = 0; nt < 4; nt++)
#pragma unroll
      for (int r = 0; r < 4; r++) {
        int row = row0 + 32 * w + 16 * im + 4 * lg + r;
        int col = 16 * nt + lm;
        float v = acc[im][nt][r] + bias[col];
        v = fmaxf(v, 0.0f) * scale;
        unsigned short h = f2h(v);
        if (p == 0)      qo[(size_t)row * 64 + col] = h;
        else if (p == 1) ko[(size_t)row * 64 + col] = h;
        else             vto[((size_t)(row >> 12) * 64 + col) * S_LEN + (row & 4095)] = h;
      }
}

// ---------------------------------------------------------------------------
// Flash attention: grid (64 q-tiles, 4 batches), 256 threads = 4 waves.
// QB=64 (wave owns 16 q rows, Q persistent in regs), KB=64 per step.
// ---------------------------------------------------------------------------
__global__ __launch_bounds__(256) void attn_kernel(
    const unsigned short* __restrict__ q, const unsigned short* __restrict__ k,
    const unsigned short* __restrict__ vT, const int* __restrict__ amask,
    float* __restrict__ out) {
  const int qtile = blockIdx.x;   // 0..63
  const int batch = blockIdx.y;   // 0..3
  const int qbase = qtile * 64;
  const int t = threadIdx.x, l = t & 63, w = t >> 6, lm = l & 15, lg = l >> 4;

  __shared__ __align__(16) unsigned short Qs[64][72];
  __shared__ __align__(16) unsigned short Ks[64][72];
  __shared__ __align__(16) unsigned short Vs[64][72];      // [d][key] (V^T)
  __shared__ __align__(16) unsigned short Ps[4][16][72];   // per-wave P

  const unsigned short* qb = q + (size_t)batch * S_LEN * 64;
  const unsigned short* kb = k + (size_t)batch * S_LEN * 64;
  const unsigned short* vb = vT + (size_t)batch * 64 * S_LEN;

  // stage Q tile (64x64 f16)
#pragma unroll
  for (int i = 0; i < 2; i++) {
    int f = t + 256 * i;
    int r = f >> 3, c8 = (f & 7) << 3;
    *(us8*)&Qs[r][c8] = *(const us8*)&qb[(size_t)(qbase + r) * 64 + c8];
  }
  __syncthreads();
  f16x8 qf[2];
  qf[0] = *(const f16x8*)&Qs[16 * w + lm][8 * lg];
  qf[1] = *(const f16x8*)&Qs[16 * w + lm][32 + 8 * lg];

  f32x4 accO[4];
#pragma unroll
  for (int i = 0; i < 4; i++)
#pragma unroll
    for (int e = 0; e < 4; e++) accO[i][e] = 0.0f;
  float m[4], lsum[4];
#pragma unroll
  for (int r = 0; r < 4; r++) { m[r] = -1e30f; lsum[r] = 0.0f; }

  const int mask = *amask;
  const int nsteps = mask ? (qtile + 1) : (S_LEN / 64);

  for (int s = 0; s < nsteps; s++) {
    const int kv0 = s * 64;
    // load K (row-major [key][dk]) and V^T (row-major [d][key]) tiles to regs
    us8 kreg[2], vreg[2];
#pragma unroll
    for (int i = 0; i < 2; i++) {
      int f = t + 256 * i;
      int r = f >> 3, c8 = (f & 7) << 3;
      kreg[i] = *(const us8*)&kb[(size_t)(kv0 + r) * 64 + c8];
      vreg[i] = *(const us8*)&vb[(size_t)r * S_LEN + kv0 + c8];
    }
    __syncthreads();  // previous iteration's reads of Ks/Vs done
#pragma unroll
    for (int i = 0; i < 2; i++) {
      int f = t + 256 * i;
      int r = f >> 3, c8 = (f & 7) << 3;
      *(us8*)&Ks[r][c8] = kreg[i];
      *(us8*)&Vs[r][c8] = vreg[i];
    }
    __syncthreads();

    // QK^T: scores [16 q][64 key] per wave
    f32x4 sc[4];
#pragma unroll
    for (int nt = 0; nt < 4; nt++) {
#pragma unroll
      for (int e = 0; e < 4; e++) sc[nt][e] = 0.0f;
      f16x8 kf0 = *(const f16x8*)&Ks[16 * nt + lm][8 * lg];
      f16x8 kf1 = *(const f16x8*)&Ks[16 * nt + lm][32 + 8 * lg];
      sc[nt] = __builtin_amdgcn_mfma_f32_16x16x32_f16(qf[0], kf0, sc[nt], 0, 0, 0);
      sc[nt] = __builtin_amdgcn_mfma_f32_16x16x32_f16(qf[1], kf1, sc[nt], 0, 0, 0);
    }

    // causal mask: only the diagonal tile needs per-element masking
    if (mask && s == qtile) {
#pragma unroll
      for (int nt = 0; nt < 4; nt++)
#pragma unroll
        for (int r = 0; r < 4; r++)
          if (kv0 + 16 * nt + lm > qbase + 16 * w + 4 * lg + r) sc[nt][r] = -1e30f;
    }

    // online softmax (rows live in 16-lane groups; reduce over lane bits 0-3)
    float p[4][4];
#pragma unroll
    for (int r = 0; r < 4; r++) {
      float mx = fmaxf(fmaxf(sc[0][r], sc[1][r]), fmaxf(sc[2][r], sc[3][r]));
      mx = fmaxf(mx, __shfl_xor(mx, 1));
      mx = fmaxf(mx, __shfl_xor(mx, 2));
      mx = fmaxf(mx, __shfl_xor(mx, 4));
      mx = fmaxf(mx, __shfl_xor(mx, 8));
      float mn = fmaxf(m[r], mx);
      float fs = __expf(m[r] - mn);
      m[r] = mn;
      float su = 0.0f;
#pragma unroll
      for (int nt = 0; nt < 4; nt++) {
        p[nt][r] = __expf(sc[nt][r] - mn);
        su += p[nt][r];
      }
      su += __shfl_xor(su, 1);
      su += __shfl_xor(su, 2);
      su += __shfl_xor(su, 4);
      su += __shfl_xor(su, 8);
      lsum[r] = lsum[r] * fs + su;
#pragma unroll
      for (int dt = 0; dt < 4; dt++) accO[dt][r] *= fs;
    }

    // P -> f16 LDS (C/D layout -> row-major [q][key] per wave)
#pragma unroll
    for (int nt = 0; nt < 4; nt++)
#pragma unroll
      for (int r = 0; r < 4; r++)
        Ps[w][4 * lg + r][16 * nt + lm] = f2h(p[nt][r]);
    __syncthreads();

    // PV: O[16 q][64 d] += P @ V
    f16x8 pf0 = *(const f16x8*)&Ps[w][lm][8 * lg];
    f16x8 pf1 = *(const f16x8*)&Ps[w][lm][32 + 8 * lg];
#pragma unroll
    for (int dt = 0; dt < 4; dt++) {
      f16x8 vf0 = *(const f16x8*)&Vs[16 * dt + lm][8 * lg];
      f16x8 vf1 = *(const f16x8*)&Vs[16 * dt + lm][32 + 8 * lg];
      accO[dt] = __builtin_amdgcn_mfma_f32_16x16x32_f16(pf0, vf0, accO[dt], 0, 0, 0);
      accO[dt] = __builtin_amdgcn_mfma_f32_16x16x32_f16(pf1, vf1, accO[dt], 0, 0, 0);
    }
  }

  // epilogue: normalize and store fp32
  float* ob = out + (size_t)batch * S_LEN * 64;
#pragma unroll
  for (int r = 0; r < 4; r++) {
    float inv = 1.0f / lsum[r];
    int row = qbase + 16 * w + 4 * lg + r;
#pragma unroll
    for (int dt = 0; dt < 4; dt++)
      ob[(size_t)row * 64 + 16 * dt + lm] = accO[dt][r] * inv;
  }
}

// ---------------------------------------------------------------------------
extern "C" void kernel_launch(void* const* d_in, const int* in_sizes, int n_in,
                              void* d_out, int out_size, void* d_ws, size_t ws_size,
                              hipStream_t stream) {
  const float* x1 = (const float*)d_in[0];
  const float* x2 = (const float*)d_in[1];
  const float* Wq = (const float*)d_in[2];
  const float* bq = (const float*)d_in[3];
  const float* Wk = (const float*)d_in[4];
  const float* bk = (const float*)d_in[5];
  const float* Wv = (const float*)d_in[6];
  const float* bv = (const float*)d_in[7];
  const int* amask = (const int*)d_in[8];

  unsigned short* qws = (unsigned short*)d_ws;                 // [16384][64] f16
  unsigned short* kws = qws + (size_t)NROW * 64;               // [16384][64] f16
  unsigned short* vtws = kws + (size_t)NROW * 64;              // [4][64][4096] f16
  float* out = (float*)d_out;

  proj_kernel<<<dim3(128, 3), 256, 0, stream>>>(x1, x2, Wq, bq, Wk, bk, Wv, bv,
                                                qws, kws, vtws);
  attn_kernel<<<dim3(64, 4), 256, 0, stream>>>(qws, kws, vtws, amask, out);
}

// Round 4
// 224.476 us; speedup vs baseline: 1.0178x; 1.0178x over previous
//
#include <hip/hip_runtime.h>

// ---------------------------------------------------------------------------
// AttentionLayer: q=relu(x1@Wq+bq)/8, k=relu(x2@Wk+bk), v=relu(x2@Wv+bv)
//   out = softmax(mask(q@k^T)) @ v          B=4, S=4096, D=512, dk=64
// Round 4 = round 3 hardened against ws overflow:
//  - partial O stored f16 (16.8 MB instead of 33.5 MB)
//  - host selects kv-split factor cch from ws_size (deterministic)
//  proj:  64-row tiles (768 blocks), W^T per-half in LDS, A global->reg,
//         V transposed via LDS for coalesced vT stores.
//  attn:  flash-decode kv-split (cch steps/unit), K/V/Q frags direct from
//         global (L1/L2-resident), zero block barriers, partials -> ws.
//  combine: merge partials per q-tile with global max, normalize, fp32 out.
// Verified layouts (round 2, absmax 0.0156):
//   A/B frag: row|col = lane&15, k = 8*(lane>>4)+e   (one b128 per frag)
//   C/D frag: col = lane&15,     row = 4*(lane>>4)+r
// ---------------------------------------------------------------------------

typedef __attribute__((ext_vector_type(8))) _Float16 f16x8;
typedef __attribute__((ext_vector_type(4))) float f32x4;
typedef __attribute__((ext_vector_type(8))) unsigned short us8;

__device__ __forceinline__ unsigned short f2h(float f) {
  _Float16 h = (_Float16)f;  // RNE
  return __builtin_bit_cast(unsigned short, h);
}
__device__ __forceinline__ float h2f(unsigned short u) {
  return (float)__builtin_bit_cast(_Float16, u);
}

#define S_LEN 4096
#define NROW 16384   // B*S

// ---------------------------------------------------------------------------
// Projection: grid (256 row-tiles x 3 proj), 256 threads (4 waves x 16 rows).
// ---------------------------------------------------------------------------
__global__ __launch_bounds__(256) void proj_kernel(
    const float* __restrict__ x1, const float* __restrict__ x2,
    const float* __restrict__ Wq, const float* __restrict__ bq,
    const float* __restrict__ Wk, const float* __restrict__ bk,
    const float* __restrict__ Wv, const float* __restrict__ bv,
    unsigned short* __restrict__ qo, unsigned short* __restrict__ ko,
    unsigned short* __restrict__ vto) {
  const int p = blockIdx.y;
  const float* __restrict__ X = (p == 0) ? x1 : x2;
  const float* __restrict__ W = (p == 0) ? Wq : (p == 1) ? Wk : Wv;
  const float* __restrict__ bias = (p == 0) ? bq : (p == 1) ? bk : bv;
  const int row0 = blockIdx.x * 64;

  // W^T half-tile [64 n][256 k] f16, row stride 264. Reused as 64x72
  // transpose buffer in the V epilogue.
  __shared__ __align__(16) unsigned short WtBuf[64 * 264];

  const int t = threadIdx.x, ln = t & 63, w = t >> 6, lm = ln & 15, lg = ln >> 4;

  f32x4 acc[4];
#pragma unroll
  for (int nt = 0; nt < 4; nt++)
#pragma unroll
    for (int e = 0; e < 4; e++) acc[nt][e] = 0.0f;

  for (int h = 0; h < 2; h++) {
    if (h) __syncthreads();  // finish frag reads of previous half
    const int kbase = h * 256;
    // stage W^T half: read W[k][n] coalesced (16 float4/thread), scatter f16
#pragma unroll
    for (int i = 0; i < 16; i++) {
      int f = t + 256 * i;                 // 0..4095 float4 slots (256 k x 16)
      int kk = f >> 4, c4 = (f & 15) << 2;
      float4 v4 = *(const float4*)&W[(size_t)(kbase + kk) * 64 + c4];
      WtBuf[(c4 + 0) * 264 + kk] = f2h(v4.x);
      WtBuf[(c4 + 1) * 264 + kk] = f2h(v4.y);
      WtBuf[(c4 + 2) * 264 + kk] = f2h(v4.z);
      WtBuf[(c4 + 3) * 264 + kk] = f2h(v4.w);
    }
    __syncthreads();

#pragma unroll
    for (int kc = 0; kc < 4; kc++) {
      const int k0 = kbase + kc * 64;      // global k of this chunk
      // A fragment straight from global fp32 -> f16 regs
      f16x8 af[2];
#pragma unroll
      for (int kk = 0; kk < 2; kk++) {
        const float* ap =
            &X[(size_t)(row0 + 16 * w + lm) * 512 + k0 + kk * 32 + 8 * lg];
        float4 a0 = *(const float4*)ap;
        float4 a1 = *(const float4*)(ap + 4);
        f16x8 v;
        v[0] = (_Float16)a0.x; v[1] = (_Float16)a0.y;
        v[2] = (_Float16)a0.z; v[3] = (_Float16)a0.w;
        v[4] = (_Float16)a1.x; v[5] = (_Float16)a1.y;
        v[6] = (_Float16)a1.z; v[7] = (_Float16)a1.w;
        af[kk] = v;
      }
#pragma unroll
      for (int nt = 0; nt < 4; nt++) {
        const int rb = (16 * nt + lm) * 264 + kc * 64;
        f16x8 b0 = *(const f16x8*)&WtBuf[rb + 8 * lg];
        f16x8 b1 = *(const f16x8*)&WtBuf[rb + 32 + 8 * lg];
        acc[nt] = __builtin_amdgcn_mfma_f32_16x16x32_f16(af[0], b0, acc[nt], 0, 0, 0);
        acc[nt] = __builtin_amdgcn_mfma_f32_16x16x32_f16(af[1], b1, acc[nt], 0, 0, 0);
      }
    }
  }

  // epilogue: bias + ReLU (+1/8 into q); q,k row-major; v transposed via LDS
  if (p < 2) {
    const float scale = (p == 0) ? 0.125f : 1.0f;
    unsigned short* __restrict__ dst = (p == 0) ? qo : ko;
#pragma unroll
    for (int nt = 0; nt < 4; nt++)
#pragma unroll
      for (int r = 0; r < 4; r++) {
        int row = row0 + 16 * w + 4 * lg + r;
        int col = 16 * nt + lm;
        float v = fmaxf(acc[nt][r] + bias[col], 0.0f) * scale;
        dst[(size_t)row * 64 + col] = f2h(v);
      }
  } else {
    __syncthreads();  // all waves done reading WtBuf; reuse as 64x72 buffer
#pragma unroll
    for (int nt = 0; nt < 4; nt++)
#pragma unroll
      for (int r = 0; r < 4; r++) {
        float v = fmaxf(acc[nt][r] + bias[16 * nt + lm], 0.0f);
        WtBuf[(16 * w + 4 * lg + r) * 72 + 16 * nt + lm] = f2h(v);
      }
    __syncthreads();
    const int d = t >> 2, s8 = (t & 3) << 4;
    us8 o0, o1;
#pragma unroll
    for (int e = 0; e < 8; e++) o0[e] = WtBuf[(s8 + e) * 72 + d];
#pragma unroll
    for (int e = 0; e < 8; e++) o1[e] = WtBuf[(s8 + 8 + e) * 72 + d];
    const int batch = row0 >> 12, sl = row0 & 4095;
    unsigned short* vp = &vto[((size_t)batch * 64 + d) * S_LEN + sl + s8];
    *(us8*)&vp[0] = o0;
    *(us8*)&vp[8] = o1;
  }
}

// ---------------------------------------------------------------------------
// Flash-decode partial: grid (64 q-tiles, npmax kv-units, 4 batches), 256 thr.
// Unit (qt,j) covers kv-steps [j*cch, min(qt, (j+1)*cch-1)]. No barriers.
// Writes unnormalized O (f16) + per-row (m, l) f32 partials.
// ---------------------------------------------------------------------------
__global__ __launch_bounds__(256) void attn_part(
    const unsigned short* __restrict__ q, const unsigned short* __restrict__ k,
    const unsigned short* __restrict__ vT, const int* __restrict__ amask,
    unsigned short* __restrict__ pO, float* __restrict__ pml,
    int cch, int npmax) {
  const int qt = blockIdx.x, j = blockIdx.y, b = blockIdx.z;
  const int mask = *amask;
  const int sb = j * cch;
  if (mask && sb > qt) return;  // unit entirely above the diagonal
  const int se = mask ? ((qt < sb + cch - 1) ? qt : sb + cch - 1) : (sb + cch - 1);

  const int t = threadIdx.x, ln = t & 63, w = t >> 6, lm = ln & 15, lg = ln >> 4;
  __shared__ __align__(16) unsigned short Ps[4][16][72];  // per-wave P tile

  const unsigned short* __restrict__ qb = q + (size_t)b * S_LEN * 64;
  const unsigned short* __restrict__ kb = k + (size_t)b * S_LEN * 64;
  const unsigned short* __restrict__ vb = vT + (size_t)b * 64 * S_LEN;

  // Q fragment for this wave's 16 rows, direct from global (persistent)
  const size_t qoff = (size_t)(qt * 64 + 16 * w + lm) * 64;
  f16x8 qf0 = *(const f16x8*)&qb[qoff + 8 * lg];
  f16x8 qf1 = *(const f16x8*)&qb[qoff + 32 + 8 * lg];

  f32x4 accO[4];
#pragma unroll
  for (int dt = 0; dt < 4; dt++)
#pragma unroll
    for (int e = 0; e < 4; e++) accO[dt][e] = 0.0f;
  float m[4], lsum[4];
#pragma unroll
  for (int r = 0; r < 4; r++) { m[r] = -1e30f; lsum[r] = 0.0f; }

  for (int s = sb; s <= se; s++) {
    const int kv0 = s * 64;
    // QK^T: K fragments direct from global (L1/L2-hot)
    f32x4 sc[4];
#pragma unroll
    for (int nt = 0; nt < 4; nt++) {
#pragma unroll
      for (int e = 0; e < 4; e++) sc[nt][e] = 0.0f;
      const unsigned short* kr = &kb[(size_t)(kv0 + 16 * nt + lm) * 64];
      f16x8 kf0 = *(const f16x8*)&kr[8 * lg];
      f16x8 kf1 = *(const f16x8*)&kr[32 + 8 * lg];
      sc[nt] = __builtin_amdgcn_mfma_f32_16x16x32_f16(qf0, kf0, sc[nt], 0, 0, 0);
      sc[nt] = __builtin_amdgcn_mfma_f32_16x16x32_f16(qf1, kf1, sc[nt], 0, 0, 0);
    }

    if (mask && s == qt) {  // diagonal tile: per-element causal mask
#pragma unroll
      for (int nt = 0; nt < 4; nt++)
#pragma unroll
        for (int r = 0; r < 4; r++)
          if (16 * nt + lm > 16 * w + 4 * lg + r) sc[nt][r] = -1e30f;
    }

    // online softmax (row lives in a 16-lane group; reduce lane bits 0-3)
    float pv[4][4];
#pragma unroll
    for (int r = 0; r < 4; r++) {
      float mx = fmaxf(fmaxf(sc[0][r], sc[1][r]), fmaxf(sc[2][r], sc[3][r]));
      mx = fmaxf(mx, __shfl_xor(mx, 1));
      mx = fmaxf(mx, __shfl_xor(mx, 2));
      mx = fmaxf(mx, __shfl_xor(mx, 4));
      mx = fmaxf(mx, __shfl_xor(mx, 8));
      float mn = fmaxf(m[r], mx);
      float fs = __expf(m[r] - mn);
      m[r] = mn;
      float su = 0.0f;
#pragma unroll
      for (int nt = 0; nt < 4; nt++) {
        pv[nt][r] = __expf(sc[nt][r] - mn);
        su += pv[nt][r];
      }
      su += __shfl_xor(su, 1);
      su += __shfl_xor(su, 2);
      su += __shfl_xor(su, 4);
      su += __shfl_xor(su, 8);
      lsum[r] = lsum[r] * fs + su;
#pragma unroll
      for (int dt = 0; dt < 4; dt++) accO[dt][r] *= fs;
    }

    // P -> per-wave LDS (C/D layout -> row-major), wave-local: no barrier
#pragma unroll
    for (int nt = 0; nt < 4; nt++)
#pragma unroll
      for (int r = 0; r < 4; r++)
        Ps[w][4 * lg + r][16 * nt + lm] = f2h(pv[nt][r]);

    f16x8 pf0 = *(const f16x8*)&Ps[w][lm][8 * lg];
    f16x8 pf1 = *(const f16x8*)&Ps[w][lm][32 + 8 * lg];
    // PV: V^T fragments direct from global
#pragma unroll
    for (int dt = 0; dt < 4; dt++) {
      const unsigned short* vr = &vb[(size_t)(16 * dt + lm) * S_LEN + kv0];
      f16x8 vf0 = *(const f16x8*)&vr[8 * lg];
      f16x8 vf1 = *(const f16x8*)&vr[32 + 8 * lg];
      accO[dt] = __builtin_amdgcn_mfma_f32_16x16x32_f16(pf0, vf0, accO[dt], 0, 0, 0);
      accO[dt] = __builtin_amdgcn_mfma_f32_16x16x32_f16(pf1, vf1, accO[dt], 0, 0, 0);
    }
  }

  // store partial (unnormalized O as f16, m/l as f32)
  const size_t ub = (size_t)(b * 64 + qt) * npmax + j;
  unsigned short* __restrict__ Op = pO + ub * 4096;
#pragma unroll
  for (int dt = 0; dt < 4; dt++)
#pragma unroll
    for (int r = 0; r < 4; r++)
      Op[(16 * w + 4 * lg + r) * 64 + 16 * dt + lm] = f2h(accO[dt][r]);
  if (lm == 0) {
    float* __restrict__ mlp = pml + ub * 128;
#pragma unroll
    for (int r = 0; r < 4; r++) {
      int row = 16 * w + 4 * lg + r;
      mlp[row * 2 + 0] = m[r];
      mlp[row * 2 + 1] = lsum[r];
    }
  }
}

// ---------------------------------------------------------------------------
// Combine: grid (64 q-tiles, 4 batches), 256 threads; thread owns a
// quarter-row (16 cols). Merges partials with global max, normalizes.
// ---------------------------------------------------------------------------
__global__ __launch_bounds__(256) void combine_kernel(
    const unsigned short* __restrict__ pO, const float* __restrict__ pml,
    const int* __restrict__ amask, float* __restrict__ out,
    int cch, int npmax) {
  const int qt = blockIdx.x, b = blockIdx.y;
  const int mask = *amask;
  const int np = mask ? (qt / cch + 1) : npmax;
  const int t = threadIdx.x;
  const int row = t >> 2, cq = (t & 3) << 4;
  const size_t base = (size_t)(b * 64 + qt) * npmax;

  float M = -1e30f;
  for (int jj = 0; jj < np; jj++)
    M = fmaxf(M, pml[(base + jj) * 128 + row * 2]);

  float L = 0.0f;
  float a[16];
#pragma unroll
  for (int e = 0; e < 16; e++) a[e] = 0.0f;
  for (int jj = 0; jj < np; jj++) {
    const float* mlp = &pml[(base + jj) * 128 + row * 2];
    float wj = __expf(mlp[0] - M);
    L += mlp[1] * wj;
    const unsigned short* Op = &pO[(base + jj) * 4096 + row * 64 + cq];
    us8 h0 = *(const us8*)&Op[0];
    us8 h1 = *(const us8*)&Op[8];
#pragma unroll
    for (int e = 0; e < 8; e++) a[e] += wj * h2f(h0[e]);
#pragma unroll
    for (int e = 0; e < 8; e++) a[8 + e] += wj * h2f(h1[e]);
  }
  const float inv = 1.0f / L;
  float* op = &out[((size_t)b * S_LEN + qt * 64 + row) * 64 + cq];
  f32x4 o;
#pragma unroll
  for (int v4 = 0; v4 < 4; v4++) {
#pragma unroll
    for (int e = 0; e < 4; e++) o[e] = a[v4 * 4 + e] * inv;
    *(f32x4*)&op[v4 * 4] = o;
  }
}

// ---------------------------------------------------------------------------
extern "C" void kernel_launch(void* const* d_in, const int* in_sizes, int n_in,
                              void* d_out, int out_size, void* d_ws, size_t ws_size,
                              hipStream_t stream) {
  const float* x1 = (const float*)d_in[0];
  const float* x2 = (const float*)d_in[1];
  const float* Wq = (const float*)d_in[2];
  const float* bq = (const float*)d_in[3];
  const float* Wk = (const float*)d_in[4];
  const float* bk = (const float*)d_in[5];
  const float* Wv = (const float*)d_in[6];
  const float* bv = (const float*)d_in[7];
  const int* amask = (const int*)d_in[8];

  unsigned short* qws = (unsigned short*)d_ws;            // [16384][64] f16, 2 MB
  unsigned short* kws = qws + (size_t)NROW * 64;          // 2 MB
  unsigned short* vtws = kws + (size_t)NROW * 64;         // [4][64][4096] f16, 2 MB
  unsigned short* pO = vtws + (size_t)NROW * 64;          // f16 partial O

  // pick largest kv-split that fits ws_size (ws_size is constant -> no
  // call-to-call behavior change; graph-capture safe)
  const size_t baseB = (size_t)NROW * 64 * 2 * 3;         // q,k,vT
  int cch = 8;
  for (; cch < 64; cch *= 2) {
    size_t units = (size_t)4 * 64 * (64 / cch);
    size_t need = baseB + units * 4096 * 2 + units * 128 * 4;
    if (need <= ws_size) break;
  }
  const int npmax = 64 / cch;
  const size_t units = (size_t)4 * 64 * npmax;
  float* pml = (float*)(pO + units * 4096);
  float* out = (float*)d_out;

  proj_kernel<<<dim3(256, 3), 256, 0, stream>>>(x1, x2, Wq, bq, Wk, bk, Wv, bv,
                                                qws, kws, vtws);
  attn_part<<<dim3(64, npmax, 4), 256, 0, stream>>>(qws, kws, vtws, amask, pO,
                                                    pml, cch, npmax);
  combine_kernel<<<dim3(64, 4), 256, 0, stream>>>(pO, pml, amask, out, cch,
                                                  npmax);
}

// Round 5
// 179.526 us; speedup vs baseline: 1.2726x; 1.2504x over previous
//
#include <hip/hip_runtime.h>

// ---------------------------------------------------------------------------
// AttentionLayer: q=relu(x1@Wq+bq)/8, k=relu(x2@Wk+bk), v=relu(x2@Wv+bv)
//   out = softmax(mask(q@k^T)) @ v          B=4, S=4096, D=512, dk=64
// Round 5: kill exposed memory latency (r4 post-mortem: occupancy 17%,
// all pipes idle, direct-global MFMA fragment reads serialized).
//  prep:  W^T -> f16 [3][64][512] once (24 blocks).
//  proj:  32-row tiles x {q | k+v fused}; X staged f32 via global_load_lds
//         double-buffer + counted vmcnt; B-frags direct from L2-hot WtT.
//  attn:  kv-split (8 steps/unit) + K/V staged once per block into
//         XOR-swizzled LDS via global_load_lds double-buffer; counted vmcnt;
//         raw s_barrier (no compiler vmcnt(0) drain).
//  combine: merge partials, normalize.
// Verified layouts (r2/r4, absmax 0.0156):
//   A/B frag: row|col = lane&15, k = 8*(lane>>4)+e   (one b128 per frag)
//   C/D frag: col = lane&15,     row = 4*(lane>>4)+r
// Swizzle (both-sides): LDS 16B-slot s holds global slot s ^ (row&7);
//   gload_lds dest linear, per-lane SOURCE pre-swizzled; reads apply same XOR.
// ---------------------------------------------------------------------------

typedef __attribute__((ext_vector_type(8))) _Float16 f16x8;
typedef __attribute__((ext_vector_type(4))) float f32x4;
typedef __attribute__((ext_vector_type(8))) unsigned short us8;

#define AS1 __attribute__((address_space(1)))
#define AS3 __attribute__((address_space(3)))

__device__ __forceinline__ void gload16(const void* g, void* l) {
  __builtin_amdgcn_global_load_lds((const AS1 unsigned int*)g,
                                   (AS3 unsigned int*)l, 16, 0, 0);
}

__device__ __forceinline__ unsigned short f2h(float f) {
  _Float16 h = (_Float16)f;  // RNE
  return __builtin_bit_cast(unsigned short, h);
}
__device__ __forceinline__ float h2f(unsigned short u) {
  return (float)__builtin_bit_cast(_Float16, u);
}
__device__ __forceinline__ f16x8 us2h(us8 v) {
  return __builtin_bit_cast(f16x8, v);
}

#define S_LEN 4096
#define NROW 16384  // B*S
#define CCH 8       // kv-steps per partial unit
#define NPMAX 8

// ---------------------------------------------------------------------------
// prep: W[512][64] f32 -> WtT[p][64 n][512 k] f16. grid (8 kchunks, 3 mats).
// ---------------------------------------------------------------------------
__global__ __launch_bounds__(256) void prep_kernel(
    const float* __restrict__ Wq, const float* __restrict__ Wk,
    const float* __restrict__ Wv, unsigned short* __restrict__ wtT) {
  const int kc = blockIdx.x, p = blockIdx.y;
  const float* __restrict__ W = (p == 0) ? Wq : (p == 1) ? Wk : Wv;
  __shared__ unsigned short T[64][72];
  const int t = threadIdx.x;
#pragma unroll
  for (int i = 0; i < 4; i++) {
    int f = t + 256 * i;  // 0..1023 float4 slots (64 k x 16)
    int kk = f >> 4, c4 = (f & 15) << 2;
    float4 v4 = *(const float4*)&W[(size_t)(kc * 64 + kk) * 64 + c4];
    T[c4 + 0][kk] = f2h(v4.x);
    T[c4 + 1][kk] = f2h(v4.y);
    T[c4 + 2][kk] = f2h(v4.z);
    T[c4 + 3][kk] = f2h(v4.w);
  }
  __syncthreads();
  const int n = t >> 2, q4 = (t & 3) << 4;
  us8 o0, o1;
#pragma unroll
  for (int e = 0; e < 8; e++) o0[e] = T[n][q4 + e];
#pragma unroll
  for (int e = 0; e < 8; e++) o1[e] = T[n][q4 + 8 + e];
  unsigned short* dst = &wtT[((size_t)p * 64 + n) * 512 + kc * 64 + q4];
  *(us8*)&dst[0] = o0;
  *(us8*)&dst[8] = o1;
}

// ---------------------------------------------------------------------------
// proj: grid (512 row-tiles of 32, 2 kinds), 128 threads = 2 waves.
// kind 0: q from x1.  kind 1: k AND v from x2 (read x2 once).
// ---------------------------------------------------------------------------
__global__ __launch_bounds__(128) void proj_kernel(
    const float* __restrict__ x1, const float* __restrict__ x2,
    const unsigned short* __restrict__ wtT, const float* __restrict__ bq,
    const float* __restrict__ bk, const float* __restrict__ bv,
    unsigned short* __restrict__ qo, unsigned short* __restrict__ ko,
    unsigned short* __restrict__ vto) {
  const int kind = blockIdx.y;
  const float* __restrict__ X = kind ? x2 : x1;
  const int row0 = blockIdx.x * 32;

  __shared__ __align__(16) float XB[2][32 * 64];  // 2 x 8KB f32

  const int t = threadIdx.x, ln = t & 63, w = t >> 6, lm = ln & 15, lg = ln >> 4;

  f32x4 acc0[4], acc1[4];
#pragma unroll
  for (int nt = 0; nt < 4; nt++)
#pragma unroll
    for (int e = 0; e < 4; e++) { acc0[nt][e] = 0.0f; acc1[nt][e] = 0.0f; }

  const unsigned short* __restrict__ wt0 =
      wtT + (size_t)(kind ? 1 : 0) * 64 * 512;
  const unsigned short* __restrict__ wt1 = wtT + (size_t)2 * 64 * 512;

  // stage one 32x64 f32 X chunk: 8 chunks of 1KB, wave w does 4w..4w+3
  auto STAGE = [&](int kc, int bi) {
#pragma unroll
    for (int cc = 0; cc < 4; cc++) {
      int c = 4 * w + cc;
      int r = 4 * c + (ln >> 4);
      int s = ln & 15;
      int sg = (s & 8) | ((s & 7) ^ (r & 7));
      gload16(&X[(size_t)(row0 + r) * 512 + kc * 64 + sg * 4],
              &XB[bi][c * 256]);
    }
  };

  STAGE(0, 0);
  for (int kc = 0; kc < 8; kc++) {
    const int bi = kc & 1;
    if (kc < 7) STAGE(kc + 1, bi ^ 1);
    // B fragments for this chunk (global, L2-hot WtT)
    us8 B0[8], B1[8];
#pragma unroll
    for (int nt = 0; nt < 4; nt++)
#pragma unroll
      for (int h = 0; h < 2; h++)
        B0[nt * 2 + h] = *(const us8*)&wt0[(size_t)(16 * nt + lm) * 512 +
                                           kc * 64 + 32 * h + 8 * lg];
    if (kind) {
#pragma unroll
      for (int nt = 0; nt < 4; nt++)
#pragma unroll
        for (int h = 0; h < 2; h++)
          B1[nt * 2 + h] = *(const us8*)&wt1[(size_t)(16 * nt + lm) * 512 +
                                             kc * 64 + 32 * h + 8 * lg];
    }
    // counted wait: allow newest (4 stage + nB B-loads); older stage done
    if (kind) {
      if (kc < 7) asm volatile("s_waitcnt vmcnt(20)" ::: "memory");
      else        asm volatile("s_waitcnt vmcnt(16)" ::: "memory");
    } else {
      if (kc < 7) asm volatile("s_waitcnt vmcnt(12)" ::: "memory");
      else        asm volatile("s_waitcnt vmcnt(8)" ::: "memory");
    }
    __builtin_amdgcn_sched_barrier(0);
    __builtin_amdgcn_s_barrier();

    // A fragments from swizzled XB + f32->f16
    const int R = 16 * w + lm;
    f16x8 af[2];
#pragma unroll
    for (int g = 0; g < 2; g++) {
      int sl0 = 8 * g + ((2 * lg) ^ (lm & 7));
      int sl1 = 8 * g + ((2 * lg + 1) ^ (lm & 7));
      f32x4 a0 = *(const f32x4*)&XB[bi][R * 64 + sl0 * 4];
      f32x4 a1 = *(const f32x4*)&XB[bi][R * 64 + sl1 * 4];
      f16x8 v;
      v[0] = (_Float16)a0[0]; v[1] = (_Float16)a0[1];
      v[2] = (_Float16)a0[2]; v[3] = (_Float16)a0[3];
      v[4] = (_Float16)a1[0]; v[5] = (_Float16)a1[1];
      v[6] = (_Float16)a1[2]; v[7] = (_Float16)a1[3];
      af[g] = v;
    }
#pragma unroll
    for (int nt = 0; nt < 4; nt++) {
      acc0[nt] = __builtin_amdgcn_mfma_f32_16x16x32_f16(af[0], us2h(B0[nt * 2 + 0]), acc0[nt], 0, 0, 0);
      acc0[nt] = __builtin_amdgcn_mfma_f32_16x16x32_f16(af[1], us2h(B0[nt * 2 + 1]), acc0[nt], 0, 0, 0);
      if (kind) {
        acc1[nt] = __builtin_amdgcn_mfma_f32_16x16x32_f16(af[0], us2h(B1[nt * 2 + 0]), acc1[nt], 0, 0, 0);
        acc1[nt] = __builtin_amdgcn_mfma_f32_16x16x32_f16(af[1], us2h(B1[nt * 2 + 1]), acc1[nt], 0, 0, 0);
      }
    }
    __builtin_amdgcn_sched_barrier(0);
    __builtin_amdgcn_s_barrier();
  }

  // epilogue
  if (kind == 0) {
#pragma unroll
    for (int nt = 0; nt < 4; nt++)
#pragma unroll
      for (int r = 0; r < 4; r++) {
        int row = row0 + 16 * w + 4 * lg + r;
        int col = 16 * nt + lm;
        float v = fmaxf(acc0[nt][r] + bq[col], 0.0f) * 0.125f;
        qo[(size_t)row * 64 + col] = f2h(v);
      }
  } else {
#pragma unroll
    for (int nt = 0; nt < 4; nt++)
#pragma unroll
      for (int r = 0; r < 4; r++) {
        int row = row0 + 16 * w + 4 * lg + r;
        int col = 16 * nt + lm;
        float v = fmaxf(acc0[nt][r] + bk[col], 0.0f);
        ko[(size_t)row * 64 + col] = f2h(v);
      }
    // v: transpose via LDS (reuse XB), coalesced us8 stores to vT
    unsigned short* TB = (unsigned short*)&XB[0][0];  // 32 x 72 f16
#pragma unroll
    for (int nt = 0; nt < 4; nt++)
#pragma unroll
      for (int r = 0; r < 4; r++) {
        float v = fmaxf(acc1[nt][r] + bv[16 * nt + lm], 0.0f);
        TB[(16 * w + 4 * lg + r) * 72 + 16 * nt + lm] = f2h(v);
      }
    __syncthreads();
    const int d = t >> 1, s0 = (t & 1) << 4;
    us8 o0, o1;
#pragma unroll
    for (int e = 0; e < 8; e++) o0[e] = TB[(s0 + e) * 72 + d];
#pragma unroll
    for (int e = 0; e < 8; e++) o1[e] = TB[(s0 + 8 + e) * 72 + d];
    const int batch = row0 >> 12, sl = row0 & 4095;
    unsigned short* vp = &vto[((size_t)batch * 64 + d) * S_LEN + sl + s0];
    *(us8*)&vp[0] = o0;
    *(us8*)&vp[8] = o1;
  }
}

// ---------------------------------------------------------------------------
// attn partial: grid (64 qt, 8 units, 4 batch), 256 thr. Unit = 8 kv-steps.
// K/V double-buffered in swizzled LDS via global_load_lds; counted vmcnt.
// ---------------------------------------------------------------------------
__global__ __launch_bounds__(256) void attn_part(
    const unsigned short* __restrict__ q, const unsigned short* __restrict__ k,
    const unsigned short* __restrict__ vT, const int* __restrict__ amask,
    unsigned short* __restrict__ pO, float* __restrict__ pml) {
  const int qt = blockIdx.x, j = blockIdx.y, b = blockIdx.z;
  const int mask = *amask;
  const int sb = j * CCH;
  if (mask && sb > qt) return;
  const int se0 = sb + CCH - 1;
  const int se = mask ? ((qt < se0) ? qt : se0) : se0;

  const int t = threadIdx.x, ln = t & 63, w = t >> 6, lm = ln & 15, lg = ln >> 4;

  __shared__ __align__(16) unsigned short KB[2][4096];  // 64 rows x 8 slots
  __shared__ __align__(16) unsigned short VB[2][4096];
  __shared__ __align__(16) unsigned short Ps[4][16][72];

  const unsigned short* __restrict__ qb = q + (size_t)b * S_LEN * 64;
  const unsigned short* __restrict__ kb = k + (size_t)b * S_LEN * 64;
  const unsigned short* __restrict__ vb = vT + (size_t)b * 64 * S_LEN;

  // Q fragments (persistent)
  const size_t qoff = (size_t)(qt * 64 + 16 * w + lm) * 64;
  f16x8 qf0 = *(const f16x8*)&qb[qoff + 8 * lg];
  f16x8 qf1 = *(const f16x8*)&qb[qoff + 32 + 8 * lg];

  // stage tile s into buffer bi: wave w stages chunks 2w,2w+1 of K and V
  const int rr = ln >> 3;               // row-within-chunk
  const int sg = (ln & 7) ^ (rr & 7);   // pre-swizzled source slot
  auto STAGE = [&](int s, int bi) {
    const int kv0 = s * 64;
#pragma unroll
    for (int cc = 0; cc < 2; cc++) {
      int c = 2 * w + cc;
      int r = 8 * c + rr;
      gload16(&kb[(size_t)(kv0 + r) * 64 + sg * 8], &KB[bi][c * 512]);
      gload16(&vb[(size_t)r * S_LEN + kv0 + sg * 8], &VB[bi][c * 512]);
    }
  };

  f32x4 accO[4];
#pragma unroll
  for (int dt = 0; dt < 4; dt++)
#pragma unroll
    for (int e = 0; e < 4; e++) accO[dt][e] = 0.0f;
  float m[4], lsum[4];
#pragma unroll
  for (int r = 0; r < 4; r++) { m[r] = -1e30f; lsum[r] = 0.0f; }

  const int sx = lm & 7;
  STAGE(sb, 0);
  for (int s = sb; s <= se; s++) {
    const int bi = (s - sb) & 1;
    if (s < se) {
      STAGE(s + 1, bi ^ 1);
      asm volatile("s_waitcnt vmcnt(4)" ::: "memory");
    } else {
      asm volatile("s_waitcnt vmcnt(0)" ::: "memory");
    }
    __builtin_amdgcn_sched_barrier(0);
    __builtin_amdgcn_s_barrier();

    // QK^T from swizzled KB
    f32x4 sc[4];
#pragma unroll
    for (int nt = 0; nt < 4; nt++) {
#pragma unroll
      for (int e = 0; e < 4; e++) sc[nt][e] = 0.0f;
      const int R = 16 * nt + lm;
      f16x8 kf0 = *(const f16x8*)&KB[bi][R * 64 + (lg ^ sx) * 8];
      f16x8 kf1 = *(const f16x8*)&KB[bi][R * 64 + ((4 + lg) ^ sx) * 8];
      sc[nt] = __builtin_amdgcn_mfma_f32_16x16x32_f16(qf0, kf0, sc[nt], 0, 0, 0);
      sc[nt] = __builtin_amdgcn_mfma_f32_16x16x32_f16(qf1, kf1, sc[nt], 0, 0, 0);
    }

    if (mask && s == qt) {
#pragma unroll
      for (int nt = 0; nt < 4; nt++)
#pragma unroll
        for (int r = 0; r < 4; r++)
          if (16 * nt + lm > 16 * w + 4 * lg + r) sc[nt][r] = -1e30f;
    }

    // online softmax
    float pv[4][4];
#pragma unroll
    for (int r = 0; r < 4; r++) {
      float mx = fmaxf(fmaxf(sc[0][r], sc[1][r]), fmaxf(sc[2][r], sc[3][r]));
      mx = fmaxf(mx, __shfl_xor(mx, 1));
      mx = fmaxf(mx, __shfl_xor(mx, 2));
      mx = fmaxf(mx, __shfl_xor(mx, 4));
      mx = fmaxf(mx, __shfl_xor(mx, 8));
      float mn = fmaxf(m[r], mx);
      float fs = __expf(m[r] - mn);
      m[r] = mn;
      float su = 0.0f;
#pragma unroll
      for (int nt = 0; nt < 4; nt++) {
        pv[nt][r] = __expf(sc[nt][r] - mn);
        su += pv[nt][r];
      }
      su += __shfl_xor(su, 1);
      su += __shfl_xor(su, 2);
      su += __shfl_xor(su, 4);
      su += __shfl_xor(su, 8);
      lsum[r] = lsum[r] * fs + su;
#pragma unroll
      for (int dt = 0; dt < 4; dt++) accO[dt][r] *= fs;
    }

    // P -> per-wave LDS (wave-local, no barrier)
#pragma unroll
    for (int nt = 0; nt < 4; nt++)
#pragma unroll
      for (int r = 0; r < 4; r++)
        Ps[w][4 * lg + r][16 * nt + lm] = f2h(pv[nt][r]);

    f16x8 pf0 = *(const f16x8*)&Ps[w][lm][8 * lg];
    f16x8 pf1 = *(const f16x8*)&Ps[w][lm][32 + 8 * lg];
    // PV from swizzled VB
#pragma unroll
    for (int dt = 0; dt < 4; dt++) {
      const int R = 16 * dt + lm;
      f16x8 vf0 = *(const f16x8*)&VB[bi][R * 64 + (lg ^ sx) * 8];
      f16x8 vf1 = *(const f16x8*)&VB[bi][R * 64 + ((4 + lg) ^ sx) * 8];
      accO[dt] = __builtin_amdgcn_mfma_f32_16x16x32_f16(pf0, vf0, accO[dt], 0, 0, 0);
      accO[dt] = __builtin_amdgcn_mfma_f32_16x16x32_f16(pf1, vf1, accO[dt], 0, 0, 0);
    }
    __builtin_amdgcn_sched_barrier(0);
    __builtin_amdgcn_s_barrier();
  }

  // store partial (unnormalized O as f16, m/l f32)
  const size_t ub = (size_t)(b * 64 + qt) * NPMAX + j;
  unsigned short* __restrict__ Op = pO + ub * 4096;
#pragma unroll
  for (int dt = 0; dt < 4; dt++)
#pragma unroll
    for (int r = 0; r < 4; r++)
      Op[(16 * w + 4 * lg + r) * 64 + 16 * dt + lm] = f2h(accO[dt][r]);
  if (lm == 0) {
    float* __restrict__ mlp = pml + ub * 128;
#pragma unroll
    for (int r = 0; r < 4; r++) {
      int row = 16 * w + 4 * lg + r;
      mlp[row * 2 + 0] = m[r];
      mlp[row * 2 + 1] = lsum[r];
    }
  }
}

// ---------------------------------------------------------------------------
// combine: grid (64 qt, 4 batch), 256 thr; thread owns a quarter-row.
// ---------------------------------------------------------------------------
__global__ __launch_bounds__(256) void combine_kernel(
    const unsigned short* __restrict__ pO, const float* __restrict__ pml,
    const int* __restrict__ amask, float* __restrict__ out) {
  const int qt = blockIdx.x, b = blockIdx.y;
  const int mask = *amask;
  const int np = mask ? (qt / CCH + 1) : NPMAX;
  const int t = threadIdx.x;
  const int row = t >> 2, cq = (t & 3) << 4;
  const size_t base = (size_t)(b * 64 + qt) * NPMAX;

  float M = -1e30f;
  for (int jj = 0; jj < np; jj++)
    M = fmaxf(M, pml[(base + jj) * 128 + row * 2]);

  float L = 0.0f;
  float a[16];
#pragma unroll
  for (int e = 0; e < 16; e++) a[e] = 0.0f;
  for (int jj = 0; jj < np; jj++) {
    const float* mlp = &pml[(base + jj) * 128 + row * 2];
    float wj = __expf(mlp[0] - M);
    L += mlp[1] * wj;
    const unsigned short* Op = &pO[(base + jj) * 4096 + row * 64 + cq];
    us8 h0 = *(const us8*)&Op[0];
    us8 h1 = *(const us8*)&Op[8];
#pragma unroll
    for (int e = 0; e < 8; e++) a[e] += wj * h2f(h0[e]);
#pragma unroll
    for (int e = 0; e < 8; e++) a[8 + e] += wj * h2f(h1[e]);
  }
  const float inv = 1.0f / L;
  float* op = &out[((size_t)b * S_LEN + qt * 64 + row) * 64 + cq];
  f32x4 o;
#pragma unroll
  for (int v4 = 0; v4 < 4; v4++) {
#pragma unroll
    for (int e = 0; e < 4; e++) o[e] = a[v4 * 4 + e] * inv;
    *(f32x4*)&op[v4 * 4] = o;
  }
}

// ---------------------------------------------------------------------------
extern "C" void kernel_launch(void* const* d_in, const int* in_sizes, int n_in,
                              void* d_out, int out_size, void* d_ws, size_t ws_size,
                              hipStream_t stream) {
  const float* x1 = (const float*)d_in[0];
  const float* x2 = (const float*)d_in[1];
  const float* Wq = (const float*)d_in[2];
  const float* bq = (const float*)d_in[3];
  const float* Wk = (const float*)d_in[4];
  const float* bk = (const float*)d_in[5];
  const float* Wv = (const float*)d_in[6];
  const float* bv = (const float*)d_in[7];
  const int* amask = (const int*)d_in[8];

  unsigned short* qws = (unsigned short*)d_ws;          // [16384][64] f16
  unsigned short* kws = qws + (size_t)NROW * 64;
  unsigned short* vtws = kws + (size_t)NROW * 64;       // [4][64][4096] f16
  unsigned short* wtT = vtws + (size_t)NROW * 64;       // [3][64][512] f16
  unsigned short* pO = wtT + (size_t)3 * 64 * 512;      // [2048][64][64] f16
  float* pml = (float*)(pO + (size_t)2048 * 4096);      // [2048][64][2] f32
  float* out = (float*)d_out;

  prep_kernel<<<dim3(8, 3), 256, 0, stream>>>(Wq, Wk, Wv, wtT);
  proj_kernel<<<dim3(512, 2), 128, 0, stream>>>(x1, x2, wtT, bq, bk, bv,
                                                qws, kws, vtws);
  attn_part<<<dim3(64, NPMAX, 4), 256, 0, stream>>>(qws, kws, vtws, amask,
                                                    pO, pml);
  combine_kernel<<<dim3(64, 4), 256, 0, stream>>>(pO, pml, amask, out);
}

// Round 6
// 165.743 us; speedup vs baseline: 1.3784x; 1.0832x over previous
//
#include <hip/hip_runtime.h>

// ---------------------------------------------------------------------------
// AttentionLayer: q=relu(x1@Wq+bq)/8, k=relu(x2@Wk+bk), v=relu(x2@Wv+bv)
//   out = softmax(mask(q@k^T)) @ v          B=4, S=4096, D=512, dk=64
// Round 6:
//  attn:  SWAPPED-OPERAND flash partial — scT=mfma(K,Q) puts a q-row's
//         scores lane-local: row max/sum = reg tree + 2 shfl (was 40 shfl).
//         accOT=mfma(V,P) keeps O^T lane-local for m/l/rescale. K/V staged
//         via global_load_lds dbuf + counted vmcnt (r5 structure kept).
//  proj:  B-frag loads issued BEFORE stage loads so compiler B-wait is
//         vmcnt(4), not vmcnt(0) — preserves the X double-buffer.
//  combine: 1024 blocks (col-quarters).
// Verified layouts (r2/r4/r5, absmax 0.0156):
//   A/B frag: row|col = lane&15, k = 8*(lane>>4)+e   (one b128 per frag)
//   C/D frag: col = lane&15,     row = 4*(lane>>4)+r
//   mfma(A,B): D[i][j] = sum_k A[i][k]*B[j][k]
// ---------------------------------------------------------------------------

typedef __attribute__((ext_vector_type(8))) _Float16 f16x8;
typedef __attribute__((ext_vector_type(4))) float f32x4;
typedef __attribute__((ext_vector_type(8))) unsigned short us8;
typedef __attribute__((ext_vector_type(4))) unsigned short us4;

#define AS1 __attribute__((address_space(1)))
#define AS3 __attribute__((address_space(3)))

__device__ __forceinline__ void gload16(const void* g, void* l) {
  __builtin_amdgcn_global_load_lds((const AS1 unsigned int*)g,
                                   (AS3 unsigned int*)l, 16, 0, 0);
}

__device__ __forceinline__ unsigned short f2h(float f) {
  _Float16 h = (_Float16)f;  // RNE
  return __builtin_bit_cast(unsigned short, h);
}
__device__ __forceinline__ float h2f(unsigned short u) {
  return (float)__builtin_bit_cast(_Float16, u);
}
__device__ __forceinline__ f16x8 us2h(us8 v) {
  return __builtin_bit_cast(f16x8, v);
}

#define S_LEN 4096
#define NROW 16384  // B*S
#define CCH 8       // kv-steps per partial unit
#define NPMAX 8

// ---------------------------------------------------------------------------
// prep: W[512][64] f32 -> WtT[p][64 n][512 k] f16. grid (8 kchunks, 3 mats).
// ---------------------------------------------------------------------------
__global__ __launch_bounds__(256) void prep_kernel(
    const float* __restrict__ Wq, const float* __restrict__ Wk,
    const float* __restrict__ Wv, unsigned short* __restrict__ wtT) {
  const int kc = blockIdx.x, p = blockIdx.y;
  const float* __restrict__ W = (p == 0) ? Wq : (p == 1) ? Wk : Wv;
  __shared__ unsigned short T[64][72];
  const int t = threadIdx.x;
#pragma unroll
  for (int i = 0; i < 4; i++) {
    int f = t + 256 * i;  // 0..1023 float4 slots (64 k x 16)
    int kk = f >> 4, c4 = (f & 15) << 2;
    float4 v4 = *(const float4*)&W[(size_t)(kc * 64 + kk) * 64 + c4];
    T[c4 + 0][kk] = f2h(v4.x);
    T[c4 + 1][kk] = f2h(v4.y);
    T[c4 + 2][kk] = f2h(v4.z);
    T[c4 + 3][kk] = f2h(v4.w);
  }
  __syncthreads();
  const int n = t >> 2, q4 = (t & 3) << 4;
  us8 o0, o1;
#pragma unroll
  for (int e = 0; e < 8; e++) o0[e] = T[n][q4 + e];
#pragma unroll
  for (int e = 0; e < 8; e++) o1[e] = T[n][q4 + 8 + e];
  unsigned short* dst = &wtT[((size_t)p * 64 + n) * 512 + kc * 64 + q4];
  *(us8*)&dst[0] = o0;
  *(us8*)&dst[8] = o1;
}

// ---------------------------------------------------------------------------
// proj: grid (512 row-tiles of 32, 2 kinds), 128 threads = 2 waves.
// kind 0: q from x1.  kind 1: k AND v from x2 (read x2 once).
// Issue order per iter: [B-frag loads (8|16)] then [stage 4] so the
// compiler's B-reg wait leaves the stage loads outstanding.
// ---------------------------------------------------------------------------
__global__ __launch_bounds__(128) void proj_kernel(
    const float* __restrict__ x1, const float* __restrict__ x2,
    const unsigned short* __restrict__ wtT, const float* __restrict__ bq,
    const float* __restrict__ bk, const float* __restrict__ bv,
    unsigned short* __restrict__ qo, unsigned short* __restrict__ ko,
    unsigned short* __restrict__ vto) {
  const int kind = blockIdx.y;
  const float* __restrict__ X = kind ? x2 : x1;
  const int row0 = blockIdx.x * 32;

  __shared__ __align__(16) float XB[2][32 * 64];  // 2 x 8KB f32

  const int t = threadIdx.x, ln = t & 63, w = t >> 6, lm = ln & 15, lg = ln >> 4;

  f32x4 acc0[4], acc1[4];
#pragma unroll
  for (int nt = 0; nt < 4; nt++)
#pragma unroll
    for (int e = 0; e < 4; e++) { acc0[nt][e] = 0.0f; acc1[nt][e] = 0.0f; }

  const unsigned short* __restrict__ wt0 =
      wtT + (size_t)(kind ? 1 : 0) * 64 * 512;
  const unsigned short* __restrict__ wt1 = wtT + (size_t)2 * 64 * 512;

  // stage one 32x64 f32 X chunk: 8 chunks of 1KB, wave w does 4w..4w+3
  auto STAGE = [&](int kc, int bi) {
#pragma unroll
    for (int cc = 0; cc < 4; cc++) {
      int c = 4 * w + cc;
      int r = 4 * c + (ln >> 4);
      int s = ln & 15;
      int sg = (s & 8) | ((s & 7) ^ (r & 7));
      gload16(&X[(size_t)(row0 + r) * 512 + kc * 64 + sg * 4],
              &XB[bi][c * 256]);
    }
  };

  STAGE(0, 0);
  for (int kc = 0; kc < 8; kc++) {
    const int bi = kc & 1;
    // B fragments FIRST (global, L2-hot WtT)
    us8 B0[8], B1[8];
#pragma unroll
    for (int nt = 0; nt < 4; nt++)
#pragma unroll
      for (int h = 0; h < 2; h++)
        B0[nt * 2 + h] = *(const us8*)&wt0[(size_t)(16 * nt + lm) * 512 +
                                           kc * 64 + 32 * h + 8 * lg];
    if (kind) {
#pragma unroll
      for (int nt = 0; nt < 4; nt++)
#pragma unroll
        for (int h = 0; h < 2; h++)
          B1[nt * 2 + h] = *(const us8*)&wt1[(size_t)(16 * nt + lm) * 512 +
                                             kc * 64 + 32 * h + 8 * lg];
    }
    // THEN next-tile stage
    if (kc < 7) STAGE(kc + 1, bi ^ 1);
    // drain only the PREVIOUS stage (oldest 4); leave B + cur stage in flight
    if (kind) {
      if (kc < 7) asm volatile("s_waitcnt vmcnt(20)" ::: "memory");
      else        asm volatile("s_waitcnt vmcnt(16)" ::: "memory");
    } else {
      if (kc < 7) asm volatile("s_waitcnt vmcnt(12)" ::: "memory");
      else        asm volatile("s_waitcnt vmcnt(8)" ::: "memory");
    }
    __builtin_amdgcn_sched_barrier(0);
    __builtin_amdgcn_s_barrier();

    // A fragments from swizzled XB + f32->f16
    const int R = 16 * w + lm;
    f16x8 af[2];
#pragma unroll
    for (int g = 0; g < 2; g++) {
      int sl0 = 8 * g + ((2 * lg) ^ (lm & 7));
      int sl1 = 8 * g + ((2 * lg + 1) ^ (lm & 7));
      f32x4 a0 = *(const f32x4*)&XB[bi][R * 64 + sl0 * 4];
      f32x4 a1 = *(const f32x4*)&XB[bi][R * 64 + sl1 * 4];
      f16x8 v;
      v[0] = (_Float16)a0[0]; v[1] = (_Float16)a0[1];
      v[2] = (_Float16)a0[2]; v[3] = (_Float16)a0[3];
      v[4] = (_Float16)a1[0]; v[5] = (_Float16)a1[1];
      v[6] = (_Float16)a1[2]; v[7] = (_Float16)a1[3];
      af[g] = v;
    }
#pragma unroll
    for (int nt = 0; nt < 4; nt++) {
      acc0[nt] = __builtin_amdgcn_mfma_f32_16x16x32_f16(af[0], us2h(B0[nt * 2 + 0]), acc0[nt], 0, 0, 0);
      acc0[nt] = __builtin_amdgcn_mfma_f32_16x16x32_f16(af[1], us2h(B0[nt * 2 + 1]), acc0[nt], 0, 0, 0);
      if (kind) {
        acc1[nt] = __builtin_amdgcn_mfma_f32_16x16x32_f16(af[0], us2h(B1[nt * 2 + 0]), acc1[nt], 0, 0, 0);
        acc1[nt] = __builtin_amdgcn_mfma_f32_16x16x32_f16(af[1], us2h(B1[nt * 2 + 1]), acc1[nt], 0, 0, 0);
      }
    }
    __builtin_amdgcn_sched_barrier(0);
    __builtin_amdgcn_s_barrier();
  }

  // epilogue
  if (kind == 0) {
#pragma unroll
    for (int nt = 0; nt < 4; nt++)
#pragma unroll
      for (int r = 0; r < 4; r++) {
        int row = row0 + 16 * w + 4 * lg + r;
        int col = 16 * nt + lm;
        float v = fmaxf(acc0[nt][r] + bq[col], 0.0f) * 0.125f;
        qo[(size_t)row * 64 + col] = f2h(v);
      }
  } else {
#pragma unroll
    for (int nt = 0; nt < 4; nt++)
#pragma unroll
      for (int r = 0; r < 4; r++) {
        int row = row0 + 16 * w + 4 * lg + r;
        int col = 16 * nt + lm;
        float v = fmaxf(acc0[nt][r] + bk[col], 0.0f);
        ko[(size_t)row * 64 + col] = f2h(v);
      }
    // v: transpose via LDS (reuse XB), coalesced us8 stores to vT
    unsigned short* TB = (unsigned short*)&XB[0][0];  // 32 x 72 f16
#pragma unroll
    for (int nt = 0; nt < 4; nt++)
#pragma unroll
      for (int r = 0; r < 4; r++) {
        float v = fmaxf(acc1[nt][r] + bv[16 * nt + lm], 0.0f);
        TB[(16 * w + 4 * lg + r) * 72 + 16 * nt + lm] = f2h(v);
      }
    __syncthreads();
    const int d = t >> 1, s0 = (t & 1) << 4;
    us8 o0, o1;
#pragma unroll
    for (int e = 0; e < 8; e++) o0[e] = TB[(s0 + e) * 72 + d];
#pragma unroll
    for (int e = 0; e < 8; e++) o1[e] = TB[(s0 + 8 + e) * 72 + d];
    const int batch = row0 >> 12, sl = row0 & 4095;
    unsigned short* vp = &vto[((size_t)batch * 64 + d) * S_LEN + sl + s0];
    *(us8*)&vp[0] = o0;
    *(us8*)&vp[8] = o1;
  }
}

// ---------------------------------------------------------------------------
// attn partial (SWAPPED): grid (64 qt, 8 units, 4 batch), 256 thr.
// scT[key][q] = mfma(K,Q): lane lm owns q-row 16w+lm; keys 16nt+4lg+r.
// accOT[d][q] = mfma(V,P): lane-local m/l/rescale, zero extra shuffles.
// ---------------------------------------------------------------------------
__global__ __launch_bounds__(256) void attn_part(
    const unsigned short* __restrict__ q, const unsigned short* __restrict__ k,
    const unsigned short* __restrict__ vT, const int* __restrict__ amask,
    unsigned short* __restrict__ pO, float* __restrict__ pml) {
  const int qt = blockIdx.x, j = blockIdx.y, b = blockIdx.z;
  const int mask = *amask;
  const int sb = j * CCH;
  if (mask && sb > qt) return;
  const int se0 = sb + CCH - 1;
  const int se = mask ? ((qt < se0) ? qt : se0) : se0;

  const int t = threadIdx.x, ln = t & 63, w = t >> 6, lm = ln & 15, lg = ln >> 4;

  __shared__ __align__(16) unsigned short KB[2][4096];  // 64 rows x 8 slots
  __shared__ __align__(16) unsigned short VB[2][4096];
  __shared__ __align__(16) unsigned short Ps[4][16][72];

  const unsigned short* __restrict__ qb = q + (size_t)b * S_LEN * 64;
  const unsigned short* __restrict__ kb = k + (size_t)b * S_LEN * 64;
  const unsigned short* __restrict__ vb = vT + (size_t)b * 64 * S_LEN;

  // Q fragments (persistent; B-operand: row=q=lm, k=8lg+e)
  const size_t qoff = (size_t)(qt * 64 + 16 * w + lm) * 64;
  f16x8 qf0 = *(const f16x8*)&qb[qoff + 8 * lg];
  f16x8 qf1 = *(const f16x8*)&qb[qoff + 32 + 8 * lg];

  // stage tile s into buffer bi: wave w stages chunks 2w,2w+1 of K and V
  const int rr = ln >> 3;               // row-within-chunk
  const int sg = (ln & 7) ^ (rr & 7);   // pre-swizzled source slot
  auto STAGE = [&](int s, int bi) {
    const int kv0 = s * 64;
#pragma unroll
    for (int cc = 0; cc < 2; cc++) {
      int c = 2 * w + cc;
      int r = 8 * c + rr;
      gload16(&kb[(size_t)(kv0 + r) * 64 + sg * 8], &KB[bi][c * 512]);
      gload16(&vb[(size_t)r * S_LEN + kv0 + sg * 8], &VB[bi][c * 512]);
    }
  };

  f32x4 accO[4];  // O^T: accO[dt][r] = O[q=16w+lm][d=16dt+4lg+r]
#pragma unroll
  for (int dt = 0; dt < 4; dt++)
#pragma unroll
    for (int e = 0; e < 4; e++) accO[dt][e] = 0.0f;
  float m0 = -1e30f, l0 = 0.0f;  // lane-local (q = 16w+lm)

  const int sx = lm & 7;
  STAGE(sb, 0);
  for (int s = sb; s <= se; s++) {
    const int bi = (s - sb) & 1;
    if (s < se) {
      STAGE(s + 1, bi ^ 1);
      asm volatile("s_waitcnt vmcnt(4)" ::: "memory");
    } else {
      asm volatile("s_waitcnt vmcnt(0)" ::: "memory");
    }
    __builtin_amdgcn_sched_barrier(0);
    __builtin_amdgcn_s_barrier();

    // QK^T swapped: scT[nt][r] = S[key=16nt+4lg+r][q=16w+lm]
    f32x4 sc[4];
#pragma unroll
    for (int nt = 0; nt < 4; nt++) {
#pragma unroll
      for (int e = 0; e < 4; e++) sc[nt][e] = 0.0f;
      const int R = 16 * nt + lm;
      f16x8 kf0 = *(const f16x8*)&KB[bi][R * 64 + (lg ^ sx) * 8];
      f16x8 kf1 = *(const f16x8*)&KB[bi][R * 64 + ((4 + lg) ^ sx) * 8];
      sc[nt] = __builtin_amdgcn_mfma_f32_16x16x32_f16(kf0, qf0, sc[nt], 0, 0, 0);
      sc[nt] = __builtin_amdgcn_mfma_f32_16x16x32_f16(kf1, qf1, sc[nt], 0, 0, 0);
    }
    // NOTE: A-frag of swapped QK is K rows: row=key=lane&15 -> keys 16nt+lm?
    // No: A row = lane&15 = lm maps K row (16nt+lm); D row = 4lg+r. The kf
    // reads above use R=16nt+lm (A rows) and D gives key=16nt+4lg+r. Both
    // index the same 16-key subtile; mapping below uses D-side (4lg+r).

    if (mask && s == qt) {  // diagonal: key_local > q_local
#pragma unroll
      for (int nt = 0; nt < 4; nt++)
#pragma unroll
        for (int r = 0; r < 4; r++)
          if (16 * nt + 4 * lg + r > 16 * w + lm) sc[nt][r] = -1e30f;
    }

    // lane-local row max over 16 scores + butterfly over lg (xor 16,32)
    float mx = fmaxf(fmaxf(fmaxf(sc[0][0], sc[0][1]), fmaxf(sc[0][2], sc[0][3])),
                     fmaxf(fmaxf(sc[1][0], sc[1][1]), fmaxf(sc[1][2], sc[1][3])));
    float mx2 = fmaxf(fmaxf(fmaxf(sc[2][0], sc[2][1]), fmaxf(sc[2][2], sc[2][3])),
                      fmaxf(fmaxf(sc[3][0], sc[3][1]), fmaxf(sc[3][2], sc[3][3])));
    mx = fmaxf(mx, mx2);
    mx = fmaxf(mx, __shfl_xor(mx, 16));
    mx = fmaxf(mx, __shfl_xor(mx, 32));
    const float mn = fmaxf(m0, mx);
    const float fs = __expf(m0 - mn);
    m0 = mn;

    float pv[4][4];
    float su = 0.0f;
#pragma unroll
    for (int nt = 0; nt < 4; nt++)
#pragma unroll
      for (int r = 0; r < 4; r++) {
        pv[nt][r] = __expf(sc[nt][r] - mn);
        su += pv[nt][r];
      }
    su += __shfl_xor(su, 16);
    su += __shfl_xor(su, 32);
    l0 = l0 * fs + su;
#pragma unroll
    for (int dt = 0; dt < 4; dt++)
#pragma unroll
      for (int e = 0; e < 4; e++) accO[dt][e] *= fs;

    // P -> Ps[q=lm][key]: 4 packed b64 writes (wave-local, no barrier)
#pragma unroll
    for (int nt = 0; nt < 4; nt++) {
      us4 w4;
#pragma unroll
      for (int r = 0; r < 4; r++) w4[r] = f2h(pv[nt][r]);
      *(us4*)&Ps[w][lm][16 * nt + 4 * lg] = w4;
    }

    // PV swapped: accO[dt] = mfma(V^T-frag, P-frag): D[d=16dt+4lg+r][q=lm]
    f16x8 pf0 = *(const f16x8*)&Ps[w][lm][8 * lg];
    f16x8 pf1 = *(const f16x8*)&Ps[w][lm][32 + 8 * lg];
#pragma unroll
    for (int dt = 0; dt < 4; dt++) {
      const int R = 16 * dt + lm;
      f16x8 vf0 = *(const f16x8*)&VB[bi][R * 64 + (lg ^ sx) * 8];
      f16x8 vf1 = *(const f16x8*)&VB[bi][R * 64 + ((4 + lg) ^ sx) * 8];
      accO[dt] = __builtin_amdgcn_mfma_f32_16x16x32_f16(vf0, pf0, accO[dt], 0, 0, 0);
      accO[dt] = __builtin_amdgcn_mfma_f32_16x16x32_f16(vf1, pf1, accO[dt], 0, 0, 0);
    }
    __builtin_amdgcn_sched_barrier(0);
    __builtin_amdgcn_s_barrier();
  }

  // store partial: O rows q=16w+lm, cols d=16dt+4lg+{0..3} (us4 stores)
  const size_t ub = (size_t)(b * 64 + qt) * NPMAX + j;
  unsigned short* __restrict__ Op = pO + ub * 4096;
#pragma unroll
  for (int dt = 0; dt < 4; dt++) {
    us4 o4;
#pragma unroll
    for (int r = 0; r < 4; r++) o4[r] = f2h(accO[dt][r]);
    *(us4*)&Op[(16 * w + lm) * 64 + 16 * dt + 4 * lg] = o4;
  }
  if (lg == 0) {
    float* __restrict__ mlp = pml + ub * 128;
    mlp[(16 * w + lm) * 2 + 0] = m0;
    mlp[(16 * w + lm) * 2 + 1] = l0;
  }
}

// ---------------------------------------------------------------------------
// combine: grid (64 qt, 4 colgroups, 4 batch), 256 thr; thread owns 4 cols
// of one row. Merges partials with global max, normalizes.
// ---------------------------------------------------------------------------
__global__ __launch_bounds__(256) void combine_kernel(
    const unsigned short* __restrict__ pO, const float* __restrict__ pml,
    const int* __restrict__ amask, float* __restrict__ out) {
  const int qt = blockIdx.x, cg = blockIdx.y, b = blockIdx.z;
  const int mask = *amask;
  const int np = mask ? (qt / CCH + 1) : NPMAX;
  const int t = threadIdx.x;
  const int row = t >> 2, c = ((t & 3) << 2) + (cg << 4);
  const size_t base = (size_t)(b * 64 + qt) * NPMAX;

  float M = -1e30f;
  for (int jj = 0; jj < np; jj++)
    M = fmaxf(M, pml[(base + jj) * 128 + row * 2]);

  float L = 0.0f;
  float a[4] = {0.f, 0.f, 0.f, 0.f};
  for (int jj = 0; jj < np; jj++) {
    const float* mlp = &pml[(base + jj) * 128 + row * 2];
    float wj = __expf(mlp[0] - M);
    L += mlp[1] * wj;
    us4 h = *(const us4*)&pO[(base + jj) * 4096 + row * 64 + c];
#pragma unroll
    for (int e = 0; e < 4; e++) a[e] += wj * h2f(h[e]);
  }
  const float inv = 1.0f / L;
  f32x4 o;
#pragma unroll
  for (int e = 0; e < 4; e++) o[e] = a[e] * inv;
  *(f32x4*)&out[((size_t)b * S_LEN + qt * 64 + row) * 64 + c] = o;
}

// ---------------------------------------------------------------------------
extern "C" void kernel_launch(void* const* d_in, const int* in_sizes, int n_in,
                              void* d_out, int out_size, void* d_ws, size_t ws_size,
                              hipStream_t stream) {
  const float* x1 = (const float*)d_in[0];
  const float* x2 = (const float*)d_in[1];
  const float* Wq = (const float*)d_in[2];
  const float* bq = (const float*)d_in[3];
  const float* Wk = (const float*)d_in[4];
  const float* bk = (const float*)d_in[5];
  const float* Wv = (const float*)d_in[6];
  const float* bv = (const float*)d_in[7];
  const int* amask = (const int*)d_in[8];

  unsigned short* qws = (unsigned short*)d_ws;          // [16384][64] f16
  unsigned short* kws = qws + (size_t)NROW * 64;
  unsigned short* vtws = kws + (size_t)NROW * 64;       // [4][64][4096] f16
  unsigned short* wtT = vtws + (size_t)NROW * 64;       // [3][64][512] f16
  unsigned short* pO = wtT + (size_t)3 * 64 * 512;      // [2048][64][64] f16
  float* pml = (float*)(pO + (size_t)2048 * 4096);      // [2048][64][2] f32
  float* out = (float*)d_out;

  prep_kernel<<<dim3(8, 3), 256, 0, stream>>>(Wq, Wk, Wv, wtT);
  proj_kernel<<<dim3(512, 2), 128, 0, stream>>>(x1, x2, wtT, bq, bk, bv,
                                                qws, kws, vtws);
  attn_part<<<dim3(64, NPMAX, 4), 256, 0, stream>>>(qws, kws, vtws, amask,
                                                    pO, pml);
  combine_kernel<<<dim3(64, 4, 4), 256, 0, stream>>>(pO, pml, amask, out);
}